// Round 6
// baseline (185.861 us; speedup 1.0000x reference)
//
#include <hip/hip_runtime.h>
#include <math.h>

#define NN 2048
#define BB 64
#define DD 512
#define NSEL 512  // NN/4

typedef float fx4 __attribute__((ext_vector_type(4)));

__device__ __forceinline__ void insert5(float v, float t[5]) {
  if (v > t[4]) {
    if (v > t[0])      { t[4]=t[3]; t[3]=t[2]; t[2]=t[1]; t[1]=t[0]; t[0]=v; }
    else if (v > t[1]) { t[4]=t[3]; t[3]=t[2]; t[2]=t[1]; t[1]=v; }
    else if (v > t[2]) { t[4]=t[3]; t[3]=t[2]; t[2]=v; }
    else if (v > t[3]) { t[4]=t[3]; t[3]=v; }
    else               { t[4]=v; }
  }
}

// ---------------------------------------------------------------------------
// Fused prep (ONE block, 1024 threads): thresholds -> keys -> stable
// descending counting sort -> top_m. Replaces 3 kernels + 2 launch gaps.
// Phase A: 16 waves x 8 rows: per-row 5th-largest via insert5 + butterfly.
// Phase B: thread t -> columns t, t+1024: key = #(att[:,c]>=thrA) +
//          #(aoff[:,c]>=thrO)  (att/aoff are L2-hot from phase A).
// Phase C: rank(n) = #(key>k) + #(same key, earlier chunk) + #(same key,
//          earlier in chunk)  == jnp.argsort(-M) stable semantics.
// ---------------------------------------------------------------------------
__global__ void __launch_bounds__(1024)
prep_kernel(const float* __restrict__ att,
            const float* __restrict__ aoff,
            int* __restrict__ top_m,
            float* __restrict__ out_tail) {
  __shared__ float thr_s[128];
  __shared__ int kl[NN];
  __shared__ int chist[32][132];
  __shared__ int htot[132];
  __shared__ int gbase[132];
  int t = threadIdx.x;             // 0..1023
  int w = t >> 6, lane = t & 63;

  for (int i = t; i < 32 * 132; i += 1024) (&chist[0][0])[i] = 0;

  // ---- Phase A: thresholds (wave w handles rows 8w..8w+7) ----
  for (int q = 0; q < 8; ++q) {
    int r = w * 8 + q;             // 0..127
    const float* rp = (r < BB) ? (att + (size_t)r * NN)
                               : (aoff + (size_t)(r - BB) * NN);
    float tt[5] = {-INFINITY, -INFINITY, -INFINITY, -INFINITY, -INFINITY};
    #pragma unroll
    for (int k = 0; k < NN / 64; ++k) insert5(rp[lane + 64 * k], tt);

    for (int off = 1; off < 64; off <<= 1) {
      float bb[5];
      #pragma unroll
      for (int k = 0; k < 5; ++k) bb[k] = __shfl_xor(tt[k], off, 64);
      float m[5];
      int ia = 0, ib = 0;
      #pragma unroll
      for (int k = 0; k < 5; ++k) {
        float av = tt[ia], bv = bb[ib];
        bool ta = (av >= bv);
        m[k] = ta ? av : bv;
        ia += ta ? 1 : 0;
        ib += ta ? 0 : 1;
      }
      #pragma unroll
      for (int k = 0; k < 5; ++k) tt[k] = m[k];
    }
    if (lane == 0) thr_s[r] = tt[4];
  }
  __syncthreads();

  // ---- Phase B: keys for columns t and t+1024 ----
  int c0 = t, c1 = t + 1024;
  int k0 = 0, k1 = 0;
  #pragma unroll 8
  for (int b = 0; b < BB; ++b) {
    float ta = thr_s[b], to = thr_s[BB + b];
    k0 += (att [(size_t)b * NN + c0] >= ta) ? 1 : 0;
    k0 += (aoff[(size_t)b * NN + c0] >= to) ? 1 : 0;
    k1 += (att [(size_t)b * NN + c1] >= ta) ? 1 : 0;
    k1 += (aoff[(size_t)b * NN + c1] >= to) ? 1 : 0;
  }
  kl[c0] = k0;
  kl[c1] = k1;
  int ch0 = t >> 6, ch1 = 16 + (t >> 6);
  atomicAdd(&chist[ch0][k0], 1);
  atomicAdd(&chist[ch1][k1], 1);
  __syncthreads();

  // ---- Phase C: stable descending counting sort ----
  if (t < 129) {
    int run = 0;
    #pragma unroll 4
    for (int c = 0; c < 32; ++c) { int v = chist[c][t]; chist[c][t] = run; run += v; }
    htot[t] = run;
  }
  __syncthreads();
  if (t == 0) {
    int acc = 0;
    for (int k = 128; k >= 0; --k) { gbase[k] = acc; acc += htot[k]; }
  }
  __syncthreads();

  int n0 = t, n1 = t + 1024;
  int pre0 = 0;
  for (int j = ch0 * 64; j < n0; ++j) pre0 += (kl[j] == k0) ? 1 : 0;
  int pre1 = 0;
  for (int j = ch1 * 64; j < n1; ++j) pre1 += (kl[j] == k1) ? 1 : 0;

  int r0 = gbase[k0] + chist[ch0][k0] + pre0;
  int r1 = gbase[k1] + chist[ch1][k1] + pre1;
  if (r0 < NSEL) { top_m[r0] = n0; out_tail[r0] = (float)n0; }
  if (r1 < NSEL) { top_m[r1] = n1; out_tail[r1] = (float)n1; }
}

// ---------------------------------------------------------------------------
// Gather (fused x+y, per-wave, depth-2 prefetch): grid = 64b x 16, 256 thr.
// Wave-private 8KB LDS row buffer; rows k+2 issued while row k is committed/
// gathered -> ~2 row-times between load issue and vmcnt wait.
// ---------------------------------------------------------------------------
#define ROW_STEP(K, PR)                                                        \
  do {                                                                         \
    int i_ = i0 + (K);                                                         \
    {                                                                          \
      fx4* mb_ = (fx4*)myrow;                                                  \
      _Pragma("unroll")                                                        \
      for (int j = 0; j < 8; ++j) mb_[lane + 64 * j] = PR[j];                  \
    }                                                                          \
    if ((K) + 2 < 8) {                                                         \
      const fx4* s_ = (const fx4*)(ybase + (size_t)cols[i_ + 2] * NN);         \
      _Pragma("unroll")                                                        \
      for (int j = 0; j < 8; ++j)                                              \
        PR[j] = __builtin_nontemporal_load(&s_[lane + 64 * j]);                \
    }                                                                          \
    {                                                                          \
      int r_ = cols[i_];                                                       \
      const fx4* xsrc_ = (const fx4*)(x + ((size_t)b * NN + r_) * DD);         \
      fx4*       xdst_ = (fx4*)(xs + ((size_t)b * NSEL + i_) * DD);            \
      _Pragma("unroll")                                                        \
      for (int j = 0; j < 2; ++j) {                                            \
        fx4 v_ = __builtin_nontemporal_load(&xsrc_[lane + 64 * j]);            \
        __builtin_nontemporal_store(v_, &xdst_[lane + 64 * j]);                \
      }                                                                        \
    }                                                                          \
    {                                                                          \
      float o_[8];                                                             \
      _Pragma("unroll")                                                        \
      for (int j = 0; j < 8; ++j) o_[j] = myrow[cols[8 * lane + j]];           \
      fx4* dst_ = (fx4*)(ys + ((size_t)b * NSEL + i_) * DD);                   \
      fx4 o0_ = {o_[0], o_[1], o_[2], o_[3]};                                  \
      fx4 o1_ = {o_[4], o_[5], o_[6], o_[7]};                                  \
      __builtin_nontemporal_store(o0_, &dst_[2 * lane]);                       \
      __builtin_nontemporal_store(o1_, &dst_[2 * lane + 1]);                   \
    }                                                                          \
  } while (0)

__global__ void __launch_bounds__(256)
gather_kernel(const float* __restrict__ x,
              const float* __restrict__ y,
              const int* __restrict__ top_m,
              float* __restrict__ xs,
              float* __restrict__ ys) {
  __shared__ float rowbuf[4][NN];   // 32KB: one 8KB row per wave
  __shared__ int cols[NSEL];
  int t = threadIdx.x;
  int w = t >> 6, lane = t & 63;
  int blk = blockIdx.x;             // 0..1023
  int b = blk >> 4;
  int iblk = blk & 15;

  cols[t]       = top_m[t];
  cols[t + 256] = top_m[t + 256];
  __syncthreads();                  // the only block barrier

  float* myrow = rowbuf[w];
  int i0 = iblk * 32 + w * 8;       // this wave's 8 rows
  const float* ybase = y + (size_t)b * NN * NN;

  fx4 prA[8], prB[8];
  {
    const fx4* sA = (const fx4*)(ybase + (size_t)cols[i0] * NN);
    #pragma unroll
    for (int j = 0; j < 8; ++j)
      prA[j] = __builtin_nontemporal_load(&sA[lane + 64 * j]);
    const fx4* sB = (const fx4*)(ybase + (size_t)cols[i0 + 1] * NN);
    #pragma unroll
    for (int j = 0; j < 8; ++j)
      prB[j] = __builtin_nontemporal_load(&sB[lane + 64 * j]);
  }

  #pragma unroll
  for (int kk = 0; kk < 4; ++kk) {
    ROW_STEP(2 * kk,     prA);
    ROW_STEP(2 * kk + 1, prB);
  }
}

// ---------------------------------------------------------------------------
extern "C" void kernel_launch(void* const* d_in, const int* in_sizes, int n_in,
                              void* d_out, int out_size, void* d_ws, size_t ws_size,
                              hipStream_t stream) {
  const float* x    = (const float*)d_in[0];   // (64, 2048, 512)
  const float* y    = (const float*)d_in[1];   // (64, 2048, 2048)
  const float* att  = (const float*)d_in[2];   // (64, 2048)
  const float* aoff = (const float*)d_in[3];   // (64, 2048)

  float* out = (float*)d_out;
  float* xs   = out;                                    // 64*512*512
  float* ysel = out + (size_t)BB * NSEL * DD;           // 64*512*512
  float* tail = ysel + (size_t)BB * NSEL * NSEL;        // 512 floats

  int* top_m = (int*)d_ws;                              // 512 ints

  hipLaunchKernelGGL(prep_kernel, dim3(1), dim3(1024), 0, stream,
                     att, aoff, top_m, tail);
  hipLaunchKernelGGL(gather_kernel, dim3(BB * 16), dim3(256), 0, stream,
                     x, y, top_m, xs, ysel);
}